// Round 2
// baseline (44547.049 us; speedup 1.0000x reference)
//
#include <hip/hip_runtime.h>
#include <hip/hip_bf16.h>

// Problem: B=64, S=512, D=1024, gates N=4096, K=2048 (x ++ h)

typedef __attribute__((ext_vector_type(8))) short bf16x8;
typedef __attribute__((ext_vector_type(16))) float f32x16;

// ---------- prep kernels ----------

// Wt[n*2048 + k] = bf16(W[k*4096 + n])   (B^T layout: 8 consecutive k per lane)
__global__ __launch_bounds__(256) void conv_w(const float* __restrict__ W,
                                              __hip_bfloat16* __restrict__ Wt) {
    size_t id = (size_t)blockIdx.x * 256 + threadIdx.x;   // < 2048*4096
    int k = (int)(id >> 12);
    int n = (int)(id & 4095);
    Wt[(size_t)n * 2048 + k] = __float2bfloat16(W[id]);
}

// Xt[(s*64+b)*1024 + d] = bf16(X[(b*512+s)*1024 + d])
__global__ __launch_bounds__(256) void conv_x(const float* __restrict__ X,
                                              __hip_bfloat16* __restrict__ Xt) {
    size_t id = (size_t)blockIdx.x * 256 + threadIdx.x;   // < 64*512*1024
    int d   = (int)(id & 1023);
    int row = (int)(id >> 10);
    int s = row >> 6;
    int b = row & 63;
    Xt[id] = __float2bfloat16(X[(((size_t)b * 512 + s) << 10) + d]);
}

// h[b*1024+k] = bf16(hx[k]) broadcast; also zero the grid-barrier counter.
__global__ __launch_bounds__(256) void init_h(const float* __restrict__ hx,
                                              __hip_bfloat16* __restrict__ h,
                                              unsigned int* __restrict__ cnt) {
    int id = blockIdx.x * 256 + threadIdx.x;              // < 65536
    h[id] = __float2bfloat16(hx[id & 1023]);
    if (id == 0) *cnt = 0u;
}

// ---------- manual grid barrier (plain launch; 256 WGs == 256 CUs co-resident) ----------
// Monotone epoch counter: arrive = device-scope atomicAdd; wait until cnt >= 256*epoch.
__device__ __forceinline__ void gbar(unsigned int* cnt, unsigned int target) {
    __syncthreads();                        // all block mem-ops retired (vmcnt drain)
    if (threadIdx.x == 0) {
        __threadfence();                    // release: writeback so other XCDs see our stores
        __hip_atomic_fetch_add(cnt, 1u, __ATOMIC_RELEASE, __HIP_MEMORY_SCOPE_AGENT);
        while (__hip_atomic_load(cnt, __ATOMIC_ACQUIRE, __HIP_MEMORY_SCOPE_AGENT) < target)
            __builtin_amdgcn_s_sleep(1);
    }
    __syncthreads();
    __threadfence();                        // acquire: invalidate stale L1/L2 before reads
}

// ---------- fused persistent recurrence ----------
// 256 WGs x 256 thr (1 WG/CU). Per step:
//   phase 1: split-K GEMM. WG b: nt=b>>1 (col tile), mt=b&1 (row block); wave kc in [0,4)
//            computes 32x32 over K-chunk kc*512. 4 partials reduced in LDS ->
//            one fp32 tile into comb[64][4096]. B-chunk (32 cols x 512 k) cached in
//            128 VGPRs across ALL 512 steps.
//   gbar
//   phase 2: WGs b<64: bias + LN + gates + state for row b; c-state in registers;
//            writes h (bf16) + out.
//   gbar
// MFMA frag (32x32x16 bf16): A row = lane&31, k = (lane>>5)*8+e ; B col = lane&31;
// D: col = lane&31, row = (r&3)+8*(r>>2)+4*(lane>>5)
__global__ __launch_bounds__(256, 1) void lstm_fused(
    const __hip_bfloat16* __restrict__ Xt,
    const __hip_bfloat16* __restrict__ Wt,
    __hip_bfloat16* __restrict__ h,
    const float* __restrict__ bias,
    const float* __restrict__ lnw,
    const float* __restrict__ lnb,
    const float* __restrict__ cx,
    float* __restrict__ comb,
    float* __restrict__ out,
    unsigned int* __restrict__ cnt)
{
    const int tid  = threadIdx.x;
    const int lane = tid & 63;
    const int wv   = tid >> 6;          // wave in WG: 0..3
    const int b    = blockIdx.x;        // 0..255

    const int nt = b >> 1;              // col tile 0..127
    const int mt = b & 1;               // row block 0..1
    const int kc = wv;                  // K chunk 0..3  (512 each)
    const int cl = lane & 31;
    const int kh = (lane >> 5) * 8;
    const int n0 = nt * 32;

    __shared__ float lds_f[4096];       // 4 x 32 x 32 split-K partials
    __shared__ float red[8];

    // ---- load this wave's B chunk into registers, once ----
    const short* bp = (const short*)Wt + (size_t)(n0 + cl) * 2048 + kc * 512 + kh;
    bf16x8 breg[32];
#pragma unroll
    for (int i = 0; i < 32; ++i) breg[i] = *(const bf16x8*)(bp + i * 16);

    // ---- A pointers ----
    const short* xbase = (const short*)Xt + (size_t)(mt * 32 + cl) * 1024 + kc * 512 + kh; // + s*65536
    const short* hrow  = (const short*)h  + (size_t)(mt * 32 + cl) * 1024 + (kc - 2) * 512 + kh; // kc>=2 only

    // ---- pointwise persistent c-state (rows owned by WGs 0..63) ----
    float cr[4];
    if (b < 64) {
#pragma unroll
        for (int q = 0; q < 4; ++q) cr[q] = cx[tid + 256 * q];
    }

    unsigned int ep = 0;

    for (int s = 0; s < 512; ++s) {
        // ================= phase 1: GEMM, split-K reduced in LDS =================
        const short* ap = (kc < 2) ? (xbase + (size_t)s * 65536) : hrow;
        f32x16 accA, accB;
#pragma unroll
        for (int i = 0; i < 16; ++i) { accA[i] = 0.f; accB[i] = 0.f; }
#pragma unroll
        for (int i = 0; i < 16; ++i) {
            bf16x8 a0 = *(const bf16x8*)(ap + i * 16);
            bf16x8 a1 = *(const bf16x8*)(ap + (i + 16) * 16);
            accA = __builtin_amdgcn_mfma_f32_32x32x16_bf16(a0, breg[i],      accA, 0, 0, 0);
            accB = __builtin_amdgcn_mfma_f32_32x32x16_bf16(a1, breg[i + 16], accB, 0, 0, 0);
        }
#pragma unroll
        for (int r = 0; r < 16; ++r) {
            int rl = (r & 3) + 8 * (r >> 2) + 4 * (lane >> 5);
            lds_f[kc * 1024 + rl * 32 + cl] = accA[r] + accB[r];
        }
        __syncthreads();
        {
            float* crow = comb + (size_t)(mt * 32) * 4096 + n0;
#pragma unroll
            for (int j = 0; j < 4; ++j) {
                int e = tid + j * 256;
                float sum = lds_f[e] + lds_f[1024 + e] + lds_f[2048 + e] + lds_f[3072 + e];
                crow[(size_t)(e >> 5) * 4096 + (e & 31)] = sum;
            }
        }
        gbar(cnt, 256u * (++ep));

        // ================= phase 2: pointwise (rows on WGs 0..63) =================
        if (b < 64) {
            const float* c0 = comb + (size_t)b * 4096;
            float v[16];
            float s1 = 0.f, s2 = 0.f;
#pragma unroll
            for (int k = 0; k < 16; ++k) {
                int col = tid + 256 * k;
                float x = c0[col] + bias[col];
                v[k] = x;
                s1 += x;
                s2 += x * x;
            }
            for (int off = 32; off; off >>= 1) {
                s1 += __shfl_down(s1, off);
                s2 += __shfl_down(s2, off);
            }
            if (lane == 0) { red[2 * wv] = s1; red[2 * wv + 1] = s2; }
            __syncthreads();
            float sum = red[0] + red[2] + red[4] + red[6];
            float ssq = red[1] + red[3] + red[5] + red[7];
            float mean = sum * (1.f / 4096.f);
            float var  = ssq * (1.f / 4096.f) - mean * mean;
            float rstd = rsqrtf(var + 1e-5f);
#pragma unroll
            for (int q = 0; q < 4; ++q) {
                int o = tid + 256 * q;
                float yi = (v[q]      - mean) * rstd * lnw[o]        + lnb[o];
                float yf = (v[q + 4]  - mean) * rstd * lnw[1024 + o] + lnb[1024 + o];
                float yo = (v[q + 8]  - mean) * rstd * lnw[2048 + o] + lnb[2048 + o];
                float yh = (v[q + 12] - mean) * rstd * lnw[3072 + o] + lnb[3072 + o];
                float ig = 1.f / (1.f + __expf(-yi));
                float fg = 1.f / (1.f + __expf(-yf));
                float og = 1.f / (1.f + __expf(-yo));
                float hd = tanhf(yh);
                float cn = fg * cr[q] + ig * hd;
                cr[q] = cn;
                float hn = og * tanhf(cn);
                h[b * 1024 + o] = __float2bfloat16(hn);
                out[(size_t)b * 524288 + (size_t)s * 1024 + o] = hn;
            }
        }
        gbar(cnt, 256u * (++ep));
    }
}

// ---------- launcher ----------
extern "C" void kernel_launch(void* const* d_in, const int* in_sizes, int n_in,
                              void* d_out, int out_size, void* d_ws, size_t ws_size,
                              hipStream_t stream) {
    const float* X   = (const float*)d_in[0];   // [64,512,1024]
    const float* W   = (const float*)d_in[1];   // [2048,4096]
    const float* bv  = (const float*)d_in[2];   // [4096]
    const float* lnw = (const float*)d_in[3];   // [4096]
    const float* lnb = (const float*)d_in[4];   // [4096]
    const float* hx  = (const float*)d_in[5];   // [1,1024]
    const float* cx  = (const float*)d_in[6];   // [1,1024]
    float* out = (float*)d_out;                 // [64,512,1024]

    char* base = (char*)d_ws;
    __hip_bfloat16* Wt   = (__hip_bfloat16*)(base);                 // 16 MB
    __hip_bfloat16* Xt   = (__hip_bfloat16*)(base + 16777216);      // 64 MB
    float*          comb = (float*)         (base + 83886080);      // 1 MB
    __hip_bfloat16* hbuf = (__hip_bfloat16*)(base + 84934656);      // 128 KB
    unsigned int*   cnt  = (unsigned int*)  (base + 85065728);      // 128 B
    // total ~85.07 MB (within the 85.3 MB footprint proven by round-0 kernel)

    conv_w<<<32768, 256, 0, stream>>>(W, Wt);
    conv_x<<<131072, 256, 0, stream>>>(X, Xt);
    init_h<<<256, 256, 0, stream>>>(hx, hbuf, cnt);

    lstm_fused<<<256, 256, 0, stream>>>(Xt, Wt, hbuf, bv, lnw, lnb, cx, comb, out, cnt);
}

// Round 3
// 16755.293 us; speedup vs baseline: 2.6587x; 2.6587x over previous
//
#include <hip/hip_runtime.h>
#include <hip/hip_bf16.h>

// Problem: B=64, S=512, D=1024, gates N=4096, K=2048 (x ++ h)

typedef __attribute__((ext_vector_type(8))) short bf16x8;
typedef __attribute__((ext_vector_type(16))) float f32x16;

// ---------- prep kernels ----------

// Wt[n*2048 + k] = bf16(W[k*4096 + n])   (B^T layout: 8 consecutive k per lane)
__global__ __launch_bounds__(256) void conv_w(const float* __restrict__ W,
                                              __hip_bfloat16* __restrict__ Wt) {
    size_t id = (size_t)blockIdx.x * 256 + threadIdx.x;   // < 2048*4096
    int k = (int)(id >> 12);
    int n = (int)(id & 4095);
    Wt[(size_t)n * 2048 + k] = __float2bfloat16(W[id]);
}

// Xt[(s*64+b)*1024 + d] = bf16(X[(b*512+s)*1024 + d])
__global__ __launch_bounds__(256) void conv_x(const float* __restrict__ X,
                                              __hip_bfloat16* __restrict__ Xt) {
    size_t id = (size_t)blockIdx.x * 256 + threadIdx.x;   // < 64*512*1024
    int d   = (int)(id & 1023);
    int row = (int)(id >> 10);
    int s = row >> 6;
    int b = row & 63;
    Xt[id] = __float2bfloat16(X[(((size_t)b * 512 + s) << 10) + d]);
}

// h[b*1024+k] = bf16(hx[k]) broadcast; also zero the grid-barrier counter.
__global__ __launch_bounds__(256) void init_h(const float* __restrict__ hx,
                                              __hip_bfloat16* __restrict__ h,
                                              unsigned int* __restrict__ cnt) {
    int id = blockIdx.x * 256 + threadIdx.x;              // < 65536
    h[id] = __float2bfloat16(hx[id & 1023]);
    if (id == 0) *cnt = 0u;
}

// ---------- manual grid barrier (plain launch; 256 WGs == 256 CUs co-resident) ----------
// Monotone epoch counter. KEY: poll with RELAXED loads (no per-iteration buffer_inv);
// exactly ONE release fence (wbl2) on arrive and ONE acquire fence (inv) on exit.
__device__ __forceinline__ void gbar(unsigned int* cnt, unsigned int target) {
    __syncthreads();                        // all block stores retired to L2
    if (threadIdx.x == 0) {
        __builtin_amdgcn_fence(__ATOMIC_RELEASE, "agent");   // wbl2: dirty L2 -> IF
        __hip_atomic_fetch_add(cnt, 1u, __ATOMIC_RELAXED, __HIP_MEMORY_SCOPE_AGENT);
        while (__hip_atomic_load(cnt, __ATOMIC_RELAXED, __HIP_MEMORY_SCOPE_AGENT) < target)
            __builtin_amdgcn_s_sleep(4);
        __builtin_amdgcn_fence(__ATOMIC_ACQUIRE, "agent");   // inv: drop stale L1/L2
    }
    __syncthreads();
}

// ---------- fused persistent recurrence ----------
// 256 WGs x 256 thr (1 WG/CU). Per step:
//   phase 1: split-K GEMM. WG b: nt=b>>1 (col tile), mt=b&1 (row block); wave kc in [0,4)
//            computes 32x32 over K-chunk kc*512. 4 partials reduced in LDS ->
//            one fp32 tile into comb[64][4096]. B-chunk (32 cols x 512 k) cached in
//            128 VGPRs across ALL 512 steps.
//   gbar
//   phase 2: WGs b<64: bias + LN + gates + state for row b; c-state in registers;
//            writes h (bf16) + out.
//   gbar
// MFMA frag (32x32x16 bf16): A row = lane&31, k = (lane>>5)*8+e ; B col = lane&31;
// D: col = lane&31, row = (r&3)+8*(r>>2)+4*(lane>>5)
__global__ __launch_bounds__(256, 1) void lstm_fused(
    const __hip_bfloat16* __restrict__ Xt,
    const __hip_bfloat16* __restrict__ Wt,
    __hip_bfloat16* __restrict__ h,
    const float* __restrict__ bias,
    const float* __restrict__ lnw,
    const float* __restrict__ lnb,
    const float* __restrict__ cx,
    float* __restrict__ comb,
    float* __restrict__ out,
    unsigned int* __restrict__ cnt)
{
    const int tid  = threadIdx.x;
    const int lane = tid & 63;
    const int wv   = tid >> 6;          // wave in WG: 0..3
    const int b    = blockIdx.x;        // 0..255

    const int nt = b >> 1;              // col tile 0..127
    const int mt = b & 1;               // row block 0..1
    const int kc = wv;                  // K chunk 0..3  (512 each)
    const int cl = lane & 31;
    const int kh = (lane >> 5) * 8;
    const int n0 = nt * 32;

    __shared__ float lds_f[4096];       // 4 x 32 x 32 split-K partials
    __shared__ float red[8];

    // ---- load this wave's B chunk into registers, once ----
    const short* bp = (const short*)Wt + (size_t)(n0 + cl) * 2048 + kc * 512 + kh;
    bf16x8 breg[32];
#pragma unroll
    for (int i = 0; i < 32; ++i) breg[i] = *(const bf16x8*)(bp + i * 16);

    // ---- A pointers ----
    const short* xbase = (const short*)Xt + (size_t)(mt * 32 + cl) * 1024 + kc * 512 + kh; // + s*65536
    const short* hrow  = (const short*)h  + (size_t)(mt * 32 + cl) * 1024 + (kc - 2) * 512 + kh; // kc>=2 only

    // ---- pointwise persistent state + parameter preloads (rows owned by WGs 0..63) ----
    float cr[4], bias_r[16], lnw_r[16], lnb_r[16];
    if (b < 64) {
#pragma unroll
        for (int q = 0; q < 4; ++q) cr[q] = cx[tid + 256 * q];
#pragma unroll
        for (int k = 0; k < 16; ++k) {
            bias_r[k] = bias[tid + 256 * k];
            lnw_r[k]  = lnw[tid + 256 * k];
            lnb_r[k]  = lnb[tid + 256 * k];
        }
    }

    unsigned int ep = 0;

    for (int s = 0; s < 512; ++s) {
        // ================= phase 1: GEMM, split-K reduced in LDS =================
        const short* ap = (kc < 2) ? (xbase + (size_t)s * 65536) : hrow;
        f32x16 accA, accB;
#pragma unroll
        for (int i = 0; i < 16; ++i) { accA[i] = 0.f; accB[i] = 0.f; }
#pragma unroll
        for (int i = 0; i < 16; ++i) {
            bf16x8 a0 = *(const bf16x8*)(ap + i * 16);
            bf16x8 a1 = *(const bf16x8*)(ap + (i + 16) * 16);
            accA = __builtin_amdgcn_mfma_f32_32x32x16_bf16(a0, breg[i],      accA, 0, 0, 0);
            accB = __builtin_amdgcn_mfma_f32_32x32x16_bf16(a1, breg[i + 16], accB, 0, 0, 0);
        }
#pragma unroll
        for (int r = 0; r < 16; ++r) {
            int rl = (r & 3) + 8 * (r >> 2) + 4 * (lane >> 5);
            lds_f[kc * 1024 + rl * 32 + cl] = accA[r] + accB[r];
        }
        __syncthreads();
        {
            float* crow = comb + (size_t)(mt * 32) * 4096 + n0;
#pragma unroll
            for (int j = 0; j < 4; ++j) {
                int e = tid + j * 256;
                float sum = lds_f[e] + lds_f[1024 + e] + lds_f[2048 + e] + lds_f[3072 + e];
                crow[(size_t)(e >> 5) * 4096 + (e & 31)] = sum;
            }
        }
        gbar(cnt, 256u * (++ep));

        // ================= phase 2: pointwise (rows on WGs 0..63) =================
        if (b < 64) {
            const float* c0 = comb + (size_t)b * 4096;
            float v[16];
            float s1 = 0.f, s2 = 0.f;
#pragma unroll
            for (int k = 0; k < 16; ++k) {
                float x = c0[tid + 256 * k] + bias_r[k];
                v[k] = x;
                s1 += x;
                s2 += x * x;
            }
            for (int off = 32; off; off >>= 1) {
                s1 += __shfl_down(s1, off);
                s2 += __shfl_down(s2, off);
            }
            if (lane == 0) { red[2 * wv] = s1; red[2 * wv + 1] = s2; }
            __syncthreads();
            float sum = red[0] + red[2] + red[4] + red[6];
            float ssq = red[1] + red[3] + red[5] + red[7];
            float mean = sum * (1.f / 4096.f);
            float var  = ssq * (1.f / 4096.f) - mean * mean;
            float rstd = rsqrtf(var + 1e-5f);
#pragma unroll
            for (int q = 0; q < 4; ++q) {
                int o = tid + 256 * q;
                float yi = (v[q]      - mean) * rstd * lnw_r[q]      + lnb_r[q];
                float yf = (v[q + 4]  - mean) * rstd * lnw_r[q + 4]  + lnb_r[q + 4];
                float yo = (v[q + 8]  - mean) * rstd * lnw_r[q + 8]  + lnb_r[q + 8];
                float yh = (v[q + 12] - mean) * rstd * lnw_r[q + 12] + lnb_r[q + 12];
                float ig = 1.f / (1.f + __expf(-yi));
                float fg = 1.f / (1.f + __expf(-yf));
                float og = 1.f / (1.f + __expf(-yo));
                float hd = tanhf(yh);
                float cn = fg * cr[q] + ig * hd;
                cr[q] = cn;
                float hn = og * tanhf(cn);
                h[b * 1024 + o] = __float2bfloat16(hn);
                out[(size_t)b * 524288 + (size_t)s * 1024 + o] = hn;
            }
        }
        if (s != 511) gbar(cnt, 256u * (++ep));
    }
}

// ---------- launcher ----------
extern "C" void kernel_launch(void* const* d_in, const int* in_sizes, int n_in,
                              void* d_out, int out_size, void* d_ws, size_t ws_size,
                              hipStream_t stream) {
    const float* X   = (const float*)d_in[0];   // [64,512,1024]
    const float* W   = (const float*)d_in[1];   // [2048,4096]
    const float* bv  = (const float*)d_in[2];   // [4096]
    const float* lnw = (const float*)d_in[3];   // [4096]
    const float* lnb = (const float*)d_in[4];   // [4096]
    const float* hx  = (const float*)d_in[5];   // [1,1024]
    const float* cx  = (const float*)d_in[6];   // [1,1024]
    float* out = (float*)d_out;                 // [64,512,1024]

    char* base = (char*)d_ws;
    __hip_bfloat16* Wt   = (__hip_bfloat16*)(base);                 // 16 MB
    __hip_bfloat16* Xt   = (__hip_bfloat16*)(base + 16777216);      // 64 MB
    float*          comb = (float*)         (base + 83886080);      // 1 MB
    __hip_bfloat16* hbuf = (__hip_bfloat16*)(base + 84934656);      // 128 KB
    unsigned int*   cnt  = (unsigned int*)  (base + 85065728);      // 128 B
    // total ~85.07 MB

    conv_w<<<32768, 256, 0, stream>>>(W, Wt);
    conv_x<<<131072, 256, 0, stream>>>(X, Xt);
    init_h<<<256, 256, 0, stream>>>(hx, hbuf, cnt);

    lstm_fused<<<256, 256, 0, stream>>>(Xt, Wt, hbuf, bv, lnw, lnb, cx, comb, out, cnt);
}

// Round 4
// 10027.432 us; speedup vs baseline: 4.4425x; 1.6709x over previous
//
#include <hip/hip_runtime.h>
#include <hip/hip_bf16.h>

// Problem: B=64, S=512, D=1024, gates N=4096, K=2048 (x ++ h)

typedef __attribute__((ext_vector_type(8))) short bf16x8;
typedef __attribute__((ext_vector_type(16))) float f32x16;

#define AT_RLX __ATOMIC_RELAXED
#define SC_AGT __HIP_MEMORY_SCOPE_AGENT

// ---------- prep kernels ----------

// Wt[n*2048 + k] = bf16(W[k*4096 + n])   (B^T layout: 8 consecutive k per lane)
__global__ __launch_bounds__(256) void conv_w(const float* __restrict__ W,
                                              __hip_bfloat16* __restrict__ Wt) {
    size_t id = (size_t)blockIdx.x * 256 + threadIdx.x;   // < 2048*4096
    int k = (int)(id >> 12);
    int n = (int)(id & 4095);
    Wt[(size_t)n * 2048 + k] = __float2bfloat16(W[id]);
}

// Xt[(s*64+b)*1024 + d] = bf16(X[(b*512+s)*1024 + d])
__global__ __launch_bounds__(256) void conv_x(const float* __restrict__ X,
                                              __hip_bfloat16* __restrict__ Xt) {
    size_t id = (size_t)blockIdx.x * 256 + threadIdx.x;   // < 64*512*1024
    int d   = (int)(id & 1023);
    int row = (int)(id >> 10);
    int s = row >> 6;
    int b = row & 63;
    Xt[id] = __float2bfloat16(X[(((size_t)b * 512 + s) << 10) + d]);
}

// h[b*1024+k] = bf16(hx[k]) broadcast; also zero the grid-barrier counter.
__global__ __launch_bounds__(256) void init_h(const float* __restrict__ hx,
                                              __hip_bfloat16* __restrict__ h,
                                              unsigned int* __restrict__ cnt) {
    int id = blockIdx.x * 256 + threadIdx.x;              // < 65536
    h[id] = __float2bfloat16(hx[id & 1023]);
    if (id == 0) *cnt = 0u;
}

// ---------- manual grid barrier: NO cache maintenance ----------
// All cross-WG data (comb, h) moves via sc0sc1 write-through/read-through relaxed
// agent atomics, so the barrier needs no wbl2/inv. __syncthreads drains vmcnt
// (write-through stores are then at the IF coherence point) before the arrive.
__device__ __forceinline__ void gbar(unsigned int* cnt, unsigned int target) {
    __syncthreads();                        // vmcnt(0): our sc-stores are globally visible
    if (threadIdx.x == 0) {
        __hip_atomic_fetch_add(cnt, 1u, AT_RLX, SC_AGT);
        while (__hip_atomic_load(cnt, AT_RLX, SC_AGT) < target)
            __builtin_amdgcn_s_sleep(1);
    }
    __syncthreads();                        // releases WG; also compiler mem barrier
}

// 16B coherent (L1/L2-bypassing) load of a bf16x8 via two 8B relaxed agent atomics
__device__ __forceinline__ bf16x8 ld_coh16(const short* p) {
    union { unsigned long long u[2]; bf16x8 v; } r;
    r.u[0] = __hip_atomic_load((const unsigned long long*)p,     AT_RLX, SC_AGT);
    r.u[1] = __hip_atomic_load((const unsigned long long*)p + 1, AT_RLX, SC_AGT);
    return r.v;
}

// ---------- fused persistent recurrence ----------
// 256 WGs x 256 thr (1 WG/CU). Per step:
//   phase 1: split-K GEMM. WG b: nt=b>>1 (col tile), mt=b&1 (row block); wave kc in [0,4)
//            computes 32x32 over K-chunk kc*512. 4 partials reduced in LDS ->
//            one fp32 tile into comb[64][4096] (sc write-through). B-chunk cached in
//            128 VGPRs across ALL 512 steps. h-waves read h via sc loads.
//   gbar
//   phase 2: WGs b<64: bias + LN + gates + state for row b; c-state in registers;
//            h written via sc stores; out via normal stores.
//   gbar
// MFMA frag (32x32x16 bf16): A row = lane&31, k = (lane>>5)*8+e ; B col = lane&31;
// D: col = lane&31, row = (r&3)+8*(r>>2)+4*(lane>>5)
__global__ __launch_bounds__(256, 1) void lstm_fused(
    const __hip_bfloat16* __restrict__ Xt,
    const __hip_bfloat16* __restrict__ Wt,
    __hip_bfloat16* __restrict__ h,
    const float* __restrict__ bias,
    const float* __restrict__ lnw,
    const float* __restrict__ lnb,
    const float* __restrict__ cx,
    float* __restrict__ comb,
    float* __restrict__ out,
    unsigned int* __restrict__ cnt)
{
    const int tid  = threadIdx.x;
    const int lane = tid & 63;
    const int wv   = tid >> 6;          // wave in WG: 0..3
    const int b    = blockIdx.x;        // 0..255

    const int nt = b >> 1;              // col tile 0..127
    const int mt = b & 1;               // row block 0..1
    const int kc = wv;                  // K chunk 0..3  (512 each)
    const int cl = lane & 31;
    const int kh = (lane >> 5) * 8;
    const int n0 = nt * 32;

    __shared__ float lds_f[4096];       // 4 x 32 x 32 split-K partials
    __shared__ float red[8];

    // ---- load this wave's B chunk into registers, once ----
    const short* bp = (const short*)Wt + (size_t)(n0 + cl) * 2048 + kc * 512 + kh;
    bf16x8 breg[32];
#pragma unroll
    for (int i = 0; i < 32; ++i) breg[i] = *(const bf16x8*)(bp + i * 16);

    // ---- A pointers ----
    const short* xbase = (const short*)Xt + (size_t)(mt * 32 + cl) * 1024 + kc * 512 + kh; // + s*65536
    const short* hrow  = (const short*)h  + (size_t)(mt * 32 + cl) * 1024 + (kc - 2) * 512 + kh; // kc>=2 only

    // ---- pointwise persistent state + parameter preloads (rows owned by WGs 0..63) ----
    float cr[4], bias_r[16], lnw_r[16], lnb_r[16];
    if (b < 64) {
#pragma unroll
        for (int q = 0; q < 4; ++q) cr[q] = cx[tid + 256 * q];
#pragma unroll
        for (int k = 0; k < 16; ++k) {
            bias_r[k] = bias[tid + 256 * k];
            lnw_r[k]  = lnw[tid + 256 * k];
            lnb_r[k]  = lnb[tid + 256 * k];
        }
    }

    unsigned int ep = 0;

    for (int s = 0; s < 512; ++s) {
        // ================= phase 1: GEMM, split-K reduced in LDS =================
        f32x16 accA, accB;
#pragma unroll
        for (int i = 0; i < 16; ++i) { accA[i] = 0.f; accB[i] = 0.f; }
        if (kc < 2) {
            const short* ap = xbase + (size_t)s * 65536;
#pragma unroll
            for (int i = 0; i < 16; ++i) {
                bf16x8 a0 = *(const bf16x8*)(ap + i * 16);
                bf16x8 a1 = *(const bf16x8*)(ap + (i + 16) * 16);
                accA = __builtin_amdgcn_mfma_f32_32x32x16_bf16(a0, breg[i],      accA, 0, 0, 0);
                accB = __builtin_amdgcn_mfma_f32_32x32x16_bf16(a1, breg[i + 16], accB, 0, 0, 0);
            }
        } else {
#pragma unroll
            for (int i = 0; i < 16; ++i) {
                bf16x8 a0 = ld_coh16(hrow + i * 16);
                bf16x8 a1 = ld_coh16(hrow + (i + 16) * 16);
                accA = __builtin_amdgcn_mfma_f32_32x32x16_bf16(a0, breg[i],      accA, 0, 0, 0);
                accB = __builtin_amdgcn_mfma_f32_32x32x16_bf16(a1, breg[i + 16], accB, 0, 0, 0);
            }
        }
#pragma unroll
        for (int r = 0; r < 16; ++r) {
            int rl = (r & 3) + 8 * (r >> 2) + 4 * (lane >> 5);
            lds_f[kc * 1024 + rl * 32 + cl] = accA[r] + accB[r];
        }
        __syncthreads();
        {
            float* crow = comb + (size_t)(mt * 32) * 4096 + n0;
#pragma unroll
            for (int j = 0; j < 4; ++j) {
                int e = tid + j * 256;
                float sum = lds_f[e] + lds_f[1024 + e] + lds_f[2048 + e] + lds_f[3072 + e];
                __hip_atomic_store(&crow[(size_t)(e >> 5) * 4096 + (e & 31)], sum,
                                   AT_RLX, SC_AGT);
            }
        }
        gbar(cnt, 256u * (++ep));

        // ================= phase 2: pointwise (rows on WGs 0..63) =================
        if (b < 64) {
            const float* c0 = comb + (size_t)b * 4096;
            float v[16];
            float s1 = 0.f, s2 = 0.f;
#pragma unroll
            for (int k = 0; k < 16; ++k) {
                float x = __hip_atomic_load(&c0[tid + 256 * k], AT_RLX, SC_AGT) + bias_r[k];
                v[k] = x;
                s1 += x;
                s2 += x * x;
            }
            for (int off = 32; off; off >>= 1) {
                s1 += __shfl_down(s1, off);
                s2 += __shfl_down(s2, off);
            }
            if (lane == 0) { red[2 * wv] = s1; red[2 * wv + 1] = s2; }
            __syncthreads();
            float sum = red[0] + red[2] + red[4] + red[6];
            float ssq = red[1] + red[3] + red[5] + red[7];
            float mean = sum * (1.f / 4096.f);
            float var  = ssq * (1.f / 4096.f) - mean * mean;
            float rstd = rsqrtf(var + 1e-5f);
#pragma unroll
            for (int q = 0; q < 4; ++q) {
                int o = tid + 256 * q;
                float yi = (v[q]      - mean) * rstd * lnw_r[q]      + lnb_r[q];
                float yf = (v[q + 4]  - mean) * rstd * lnw_r[q + 4]  + lnb_r[q + 4];
                float yo = (v[q + 8]  - mean) * rstd * lnw_r[q + 8]  + lnb_r[q + 8];
                float yh = (v[q + 12] - mean) * rstd * lnw_r[q + 12] + lnb_r[q + 12];
                float ig = 1.f / (1.f + __expf(-yi));
                float fg = 1.f / (1.f + __expf(-yf));
                float og = 1.f / (1.f + __expf(-yo));
                float hd = tanhf(yh);
                float cn = fg * cr[q] + ig * hd;
                cr[q] = cn;
                float hn = og * tanhf(cn);
                unsigned short hb = __builtin_bit_cast(unsigned short, __float2bfloat16(hn));
                __hip_atomic_store((unsigned short*)h + b * 1024 + o, hb, AT_RLX, SC_AGT);
                out[(size_t)b * 524288 + (size_t)s * 1024 + o] = hn;
            }
        }
        if (s != 511) gbar(cnt, 256u * (++ep));
    }
}

// ---------- launcher ----------
extern "C" void kernel_launch(void* const* d_in, const int* in_sizes, int n_in,
                              void* d_out, int out_size, void* d_ws, size_t ws_size,
                              hipStream_t stream) {
    const float* X   = (const float*)d_in[0];   // [64,512,1024]
    const float* W   = (const float*)d_in[1];   // [2048,4096]
    const float* bv  = (const float*)d_in[2];   // [4096]
    const float* lnw = (const float*)d_in[3];   // [4096]
    const float* lnb = (const float*)d_in[4];   // [4096]
    const float* hx  = (const float*)d_in[5];   // [1,1024]
    const float* cx  = (const float*)d_in[6];   // [1,1024]
    float* out = (float*)d_out;                 // [64,512,1024]

    char* base = (char*)d_ws;
    __hip_bfloat16* Wt   = (__hip_bfloat16*)(base);                 // 16 MB
    __hip_bfloat16* Xt   = (__hip_bfloat16*)(base + 16777216);      // 64 MB
    float*          comb = (float*)         (base + 83886080);      // 1 MB
    __hip_bfloat16* hbuf = (__hip_bfloat16*)(base + 84934656);      // 128 KB
    unsigned int*   cnt  = (unsigned int*)  (base + 85065728);      // 128 B
    // total ~85.07 MB

    conv_w<<<32768, 256, 0, stream>>>(W, Wt);
    conv_x<<<131072, 256, 0, stream>>>(X, Xt);
    init_h<<<256, 256, 0, stream>>>(hx, hbuf, cnt);

    lstm_fused<<<256, 256, 0, stream>>>(Xt, Wt, hbuf, bv, lnw, lnb, cx, comb, out, cnt);
}

// Round 6
// 6662.365 us; speedup vs baseline: 6.6864x; 1.5051x over previous
//
#include <hip/hip_runtime.h>
#include <hip/hip_bf16.h>

// Problem: B=64, S=512, D=1024, gates N=4096, K=2048 (x ++ h)

typedef __attribute__((ext_vector_type(8))) short bf16x8;
typedef __attribute__((ext_vector_type(16))) float f32x16;

#define AT_RLX __ATOMIC_RELAXED
#define SC_AGT __HIP_MEMORY_SCOPE_AGENT

// ---------- prep kernels ----------

// Wt[n*2048 + k] = bf16(W[k*4096 + n])   (B^T layout: 8 consecutive k per lane)
__global__ __launch_bounds__(256) void conv_w(const float* __restrict__ W,
                                              __hip_bfloat16* __restrict__ Wt) {
    size_t id = (size_t)blockIdx.x * 256 + threadIdx.x;   // < 2048*4096
    int k = (int)(id >> 12);
    int n = (int)(id & 4095);
    Wt[(size_t)n * 2048 + k] = __float2bfloat16(W[id]);
}

// Xt[(s*64+b)*1024 + d] = bf16(X[(b*512+s)*1024 + d])
__global__ __launch_bounds__(256) void conv_x(const float* __restrict__ X,
                                              __hip_bfloat16* __restrict__ Xt) {
    size_t id = (size_t)blockIdx.x * 256 + threadIdx.x;   // < 64*512*1024
    int d   = (int)(id & 1023);
    int row = (int)(id >> 10);
    int s = row >> 6;
    int b = row & 63;
    Xt[id] = __float2bfloat16(X[(((size_t)b * 512 + s) << 10) + d]);
}

// h[b*1024+k] = bf16(hx[k]) broadcast; zero the epoch flags (MUST reset every launch).
__global__ __launch_bounds__(256) void init_h(const float* __restrict__ hx,
                                              __hip_bfloat16* __restrict__ h,
                                              unsigned int* __restrict__ cflag,
                                              unsigned int* __restrict__ hflag) {
    int id = blockIdx.x * 256 + threadIdx.x;              // < 65536
    h[id] = __float2bfloat16(hx[id & 1023]);
    if (id < 4096) cflag[id] = 0u;                        // 256 flags x 16 u32 pad
    else if (id < 5120) hflag[id - 4096] = 0u;            // 64 flags x 16 u32 pad
}

// ---------- coherence-point primitives ----------
// 16B coherent load of a bf16x8 via two 8B relaxed agent atomic loads (IF-read)
__device__ __forceinline__ bf16x8 ld_coh16(const short* p) {
    union { unsigned long long u[2]; bf16x8 v; } r;
    r.u[0] = __hip_atomic_load((const unsigned long long*)p,     AT_RLX, SC_AGT);
    r.u[1] = __hip_atomic_load((const unsigned long long*)p + 1, AT_RLX, SC_AGT);
    return r.v;
}
// 8B coherent load of two adjacent f32
__device__ __forceinline__ float2 ld_coh8f(const float* p) {
    union { unsigned long long u; float2 f; } c;
    c.u = __hip_atomic_load((const unsigned long long*)p, AT_RLX, SC_AGT);
    return c.f;
}
// 8B write EXECUTED AT the IF coherence point: returning agent-scope exchange.
// vmcnt for the op only clears when the old value returns from IF -> after a
// vmcnt(0) drain the new data is provably globally visible (no ack-vs-arrival gap).
__device__ __forceinline__ void xchg8f(float* p, float lo, float hi) {
    union { float f[2]; unsigned long long u; } c;
    c.f[0] = lo; c.f[1] = hi;
    unsigned long long old =
        __hip_atomic_exchange((unsigned long long*)p, c.u, AT_RLX, SC_AGT);
    asm volatile("" :: "v"(old));   // keep the returning form alive (rule #17)
}
// 4B coherence-point write (packed 2x bf16)
__device__ __forceinline__ void xchg4(unsigned int* p, unsigned int v) {
    unsigned int old = __hip_atomic_exchange(p, v, AT_RLX, SC_AGT);
    asm volatile("" :: "v"(old));
}

// ---------- fused persistent recurrence: flag-pipelined, NO global barrier ----------
// 256 WGs x 256 thr (1 WG/CU). WG b: nt=b>>1 (col tile), mt=b&1 (row block).
// cflag[wg] = s+1 after wg's comb(s) tile is AT the coherence point (exchanges+drain).
// hflag[r]  = s+1 after row-WG r's h(s) is AT the coherence point.
// Step s:
//   waves kc<2: x-part MFMAs immediately (overlaps phase 2(s-1) of row-WGs).
//   waves kc>=2: per-lane poll hflag[row] >= s, then h-part MFMAs (IF loads).
//   LDS split-K reduce -> comb 8B-exchanges -> syncthreads (vmcnt0) -> cflag = s+1.
//   WGs b<64: threads<128 poll cflag of their 128 producers, bias+LN+gates+state,
//   h packed 4B-exchanges, drain, hflag[b] = s+1.
// Hazards: comb WAR safe (h-poll of exactly comb(s)'s readers gates the WG via
// syncthreads before comb(s+1) stores); h WAR safe (cflag poll covers exactly the
// readers of the h rows this WG owns).
__global__ __launch_bounds__(256, 1) void lstm_fused(
    const __hip_bfloat16* __restrict__ Xt,
    const __hip_bfloat16* __restrict__ Wt,
    __hip_bfloat16* __restrict__ h,
    const float* __restrict__ bias,
    const float* __restrict__ lnw,
    const float* __restrict__ lnb,
    const float* __restrict__ cx,
    float* __restrict__ comb,
    float* __restrict__ out,
    unsigned int* __restrict__ cflag,
    unsigned int* __restrict__ hflag)
{
    const int tid  = threadIdx.x;
    const int lane = tid & 63;
    const int wv   = tid >> 6;          // wave in WG: 0..3
    const int b    = blockIdx.x;        // 0..255

    const int nt = b >> 1;              // col tile 0..127
    const int mt = b & 1;               // row block 0..1
    const int kc = wv;                  // K chunk 0..3  (512 each)
    const int cl = lane & 31;
    const int kh = (lane >> 5) * 8;
    const int n0 = nt * 32;

    __shared__ float lds_f[4096];       // 4 x 32 x 32 split-K partials
    __shared__ float red[8];

    // ---- load this wave's B chunk into registers, once ----
    const short* bp = (const short*)Wt + (size_t)(n0 + cl) * 2048 + kc * 512 + kh;
    bf16x8 breg[32];
#pragma unroll
    for (int i = 0; i < 32; ++i) breg[i] = *(const bf16x8*)(bp + i * 16);

    // ---- A pointers ----
    const short* xbase = (const short*)Xt + (size_t)(mt * 32 + cl) * 1024 + kc * 512 + kh; // + s*65536
    const short* hrow  = (const short*)h  + (size_t)(mt * 32 + cl) * 1024 + (kc - 2) * 512 + kh; // kc>=2
    const unsigned int* myhf = &hflag[(mt * 32 + cl) * 16];   // h-row flag this lane needs
    const unsigned int* mycf = &cflag[(2 * (tid & 127) + (b >> 5)) * 16]; // consumer poll target

    // ---- pointwise persistent state + parameter preloads (rows owned by WGs 0..63) ----
    // thread t owns o-cols o_u = (u>>1)*512 + 2t + (u&1), u in [0,4)  (pair-adjacent
    // for packed 4B h-exchanges and 8B comb loads). v[4g+u] = comb[1024g + o_u].
    float cr[4], bias_r[16], lnw_r[16], lnb_r[16];
    if (b < 64) {
#pragma unroll
        for (int u = 0; u < 4; ++u) cr[u] = cx[(u >> 1) * 512 + 2 * tid + (u & 1)];
#pragma unroll
        for (int k = 0; k < 16; ++k) {
            int col = 512 * (k >> 1) + 2 * tid + (k & 1);  // k = 2j+i ; gate g = k>>2... (=4g+u view)
            bias_r[k] = bias[col];
            lnw_r[k]  = lnw[col];
            lnb_r[k]  = lnb[col];
        }
    }

    for (int s = 0; s < 512; ++s) {
        // ================= phase 1: GEMM, split-K reduced in LDS =================
        f32x16 accA, accB;
#pragma unroll
        for (int i = 0; i < 16; ++i) { accA[i] = 0.f; accB[i] = 0.f; }
        if (kc < 2) {
            const short* ap = xbase + (size_t)s * 65536;
#pragma unroll
            for (int i = 0; i < 16; ++i) {
                bf16x8 a0 = *(const bf16x8*)(ap + i * 16);
                bf16x8 a1 = *(const bf16x8*)(ap + (i + 16) * 16);
                accA = __builtin_amdgcn_mfma_f32_32x32x16_bf16(a0, breg[i],      accA, 0, 0, 0);
                accB = __builtin_amdgcn_mfma_f32_32x32x16_bf16(a1, breg[i + 16], accB, 0, 0, 0);
            }
        } else {
            // wait for h(s-1): per-lane poll of the one row flag this lane reads
            while (__hip_atomic_load(myhf, AT_RLX, SC_AGT) < (unsigned int)s)
                __builtin_amdgcn_s_sleep(1);
            asm volatile("" ::: "memory");
#pragma unroll
            for (int i = 0; i < 16; ++i) {
                bf16x8 a0 = ld_coh16(hrow + i * 16);
                bf16x8 a1 = ld_coh16(hrow + (i + 16) * 16);
                accA = __builtin_amdgcn_mfma_f32_32x32x16_bf16(a0, breg[i],      accA, 0, 0, 0);
                accB = __builtin_amdgcn_mfma_f32_32x32x16_bf16(a1, breg[i + 16], accB, 0, 0, 0);
            }
        }
#pragma unroll
        for (int r = 0; r < 16; ++r) {
            int rl = (r & 3) + 8 * (r >> 2) + 4 * (lane >> 5);
            lds_f[kc * 1024 + rl * 32 + cl] = accA[r] + accB[r];
        }
        __syncthreads();
        {
            float* crow = comb + (size_t)(mt * 32) * 4096 + n0;
#pragma unroll
            for (int half = 0; half < 2; ++half) {
                int e = 2 * tid + half * 512;           // even -> 8B aligned pair
                float2 p0 = *(const float2*)&lds_f[e];
                float2 p1 = *(const float2*)&lds_f[1024 + e];
                float2 p2 = *(const float2*)&lds_f[2048 + e];
                float2 p3 = *(const float2*)&lds_f[3072 + e];
                xchg8f(&crow[(size_t)(e >> 5) * 4096 + (e & 31)],
                       p0.x + p1.x + p2.x + p3.x,
                       p0.y + p1.y + p2.y + p3.y);
            }
        }
        __syncthreads();   // vmcnt(0): exchanges returned from IF -> data globally visible
        if (tid == 0)
            __hip_atomic_store(&cflag[b * 16], (unsigned int)(s + 1), AT_RLX, SC_AGT);

        // ================= phase 2: pointwise (rows on WGs 0..63) =================
        if (b < 64) {
            if (tid < 128) {   // one thread per producer WG of this row-block
                while (__hip_atomic_load(mycf, AT_RLX, SC_AGT) < (unsigned int)(s + 1))
                    __builtin_amdgcn_s_sleep(1);
            }
            __syncthreads();
            asm volatile("" ::: "memory");
            const float* c0 = comb + (size_t)b * 4096;
            float v[16];
            float s1 = 0.f, s2 = 0.f;
#pragma unroll
            for (int j = 0; j < 8; ++j) {
                float2 x2 = ld_coh8f(&c0[512 * j + 2 * tid]);
                float x0 = x2.x + bias_r[2 * j];
                float x1 = x2.y + bias_r[2 * j + 1];
                v[2 * j]     = x0;
                v[2 * j + 1] = x1;
                s1 += x0 + x1;
                s2 += x0 * x0 + x1 * x1;
            }
            for (int off = 32; off; off >>= 1) {
                s1 += __shfl_down(s1, off);
                s2 += __shfl_down(s2, off);
            }
            if (lane == 0) { red[2 * wv] = s1; red[2 * wv + 1] = s2; }
            __syncthreads();
            float sum = red[0] + red[2] + red[4] + red[6];
            float ssq = red[1] + red[3] + red[5] + red[7];
            float mean = sum * (1.f / 4096.f);
            float var  = ssq * (1.f / 4096.f) - mean * mean;
            float rstd = rsqrtf(var + 1e-5f);
            float hn[4];
#pragma unroll
            for (int u = 0; u < 4; ++u) {
                int o = (u >> 1) * 512 + 2 * tid + (u & 1);
                float yi = (v[u]      - mean) * rstd * lnw_r[u]      + lnb_r[u];
                float yf = (v[u + 4]  - mean) * rstd * lnw_r[u + 4]  + lnb_r[u + 4];
                float yo = (v[u + 8]  - mean) * rstd * lnw_r[u + 8]  + lnb_r[u + 8];
                float yh = (v[u + 12] - mean) * rstd * lnw_r[u + 12] + lnb_r[u + 12];
                float ig = 1.f / (1.f + __expf(-yi));
                float fg = 1.f / (1.f + __expf(-yf));
                float og = 1.f / (1.f + __expf(-yo));
                float hd = tanhf(yh);
                float cn = fg * cr[u] + ig * hd;
                cr[u] = cn;
                hn[u] = og * tanhf(cn);
                out[(size_t)b * 524288 + (size_t)s * 1024 + o] = hn[u];
            }
            // packed h writes at the coherence point: cols (2t,2t+1) and (512+2t,+1)
            unsigned short h0 = __builtin_bit_cast(unsigned short, __float2bfloat16(hn[0]));
            unsigned short h1 = __builtin_bit_cast(unsigned short, __float2bfloat16(hn[1]));
            unsigned short h2 = __builtin_bit_cast(unsigned short, __float2bfloat16(hn[2]));
            unsigned short h3 = __builtin_bit_cast(unsigned short, __float2bfloat16(hn[3]));
            unsigned short* hb = (unsigned short*)h + b * 1024;
            xchg4((unsigned int*)(hb + 2 * tid),       (unsigned int)h0 | ((unsigned int)h1 << 16));
            xchg4((unsigned int*)(hb + 512 + 2 * tid), (unsigned int)h2 | ((unsigned int)h3 << 16));
            __syncthreads();   // vmcnt(0): h(s) at coherence point
            if (tid == 0)
                __hip_atomic_store(&hflag[b * 16], (unsigned int)(s + 1), AT_RLX, SC_AGT);
        }
    }
}

// ---------- launcher ----------
extern "C" void kernel_launch(void* const* d_in, const int* in_sizes, int n_in,
                              void* d_out, int out_size, void* d_ws, size_t ws_size,
                              hipStream_t stream) {
    const float* X   = (const float*)d_in[0];   // [64,512,1024]
    const float* W   = (const float*)d_in[1];   // [2048,4096]
    const float* bv  = (const float*)d_in[2];   // [4096]
    const float* lnw = (const float*)d_in[3];   // [4096]
    const float* lnb = (const float*)d_in[4];   // [4096]
    const float* hx  = (const float*)d_in[5];   // [1,1024]
    const float* cx  = (const float*)d_in[6];   // [1,1024]
    float* out = (float*)d_out;                 // [64,512,1024]

    char* base = (char*)d_ws;
    __hip_bfloat16* Wt    = (__hip_bfloat16*)(base);                 // 16 MB
    __hip_bfloat16* Xt    = (__hip_bfloat16*)(base + 16777216);      // 64 MB
    float*          comb  = (float*)         (base + 83886080);      // 1 MB
    __hip_bfloat16* hbuf  = (__hip_bfloat16*)(base + 84934656);      // 128 KB
    unsigned int*   cflag = (unsigned int*)  (base + 85065728);      // 16 KB (256 x 64B)
    unsigned int*   hflag = (unsigned int*)  (base + 85082112);      // 4 KB  (64 x 64B)
    // total ~85.09 MB

    conv_w<<<32768, 256, 0, stream>>>(W, Wt);
    conv_x<<<131072, 256, 0, stream>>>(X, Xt);
    init_h<<<256, 256, 0, stream>>>(hx, hbuf, cflag, hflag);

    lstm_fused<<<256, 256, 0, stream>>>(Xt, Wt, hbuf, bv, lnw, lnb, cx, comb, out,
                                        cflag, hflag);
}